// Round 6
// baseline (682.126 us; speedup 1.0000x reference)
//
#include <hip/hip_runtime.h>
#include <cstdint>
#include <cstddef>

#define NROWS 16384
#define KDIM  16384
#define EPSF  1e-7f
#define MINN  1e-15f
#define MAXN  1e6f
#define BM    32               /* rows per block */
#define BK2   64               /* K per step */
#define NSTEP2 (KDIM/BK2)      /* 256 */
#define APG   528              /* A page stride: 32*16B + 16B pad */
#define BPG   1040             /* B page stride: 64*16B + 16B pad */
#define ABUF  (8*APG)          /* 4224 */
#define BBUF  (8*BPG)          /* 8320 */

typedef __attribute__((ext_vector_type(8))) short short8;
typedef __attribute__((ext_vector_type(4))) float f32x4;
typedef __attribute__((ext_vector_type(4))) unsigned short u16x4;

// barrier WITHOUT vmcnt(0) drain: LDS visibility only (T4 — never drain vmcnt in main loop)
#define BARL() do { \
  asm volatile("s_waitcnt lgkmcnt(0)" ::: "memory"); \
  __builtin_amdgcn_s_barrier(); \
  asm volatile("" ::: "memory"); \
} while(0)

__device__ __forceinline__ unsigned short f2bf(float f){
  union { float f; unsigned u; } c; c.f = f;
  unsigned u = c.u;
  unsigned r = (u + 0x7FFFu + ((u >> 16) & 1u)) >> 16;   // RNE
  return (unsigned short)r;
}

__device__ __forceinline__ float wredsum(float v){
  v += __shfl_xor(v, 1);
  v += __shfl_xor(v, 2);
  v += __shfl_xor(v, 4);
  v += __shfl_xor(v, 8);
  v += __shfl_xor(v, 16);
  v += __shfl_xor(v, 32);
  return v;
}

// ---- ub = logmap0(proj(expmap0(proj_tan0(b)))) for b1 (wave0) and b2 (wave1)
__global__ __launch_bounds__(128) void k_bias(const float* __restrict__ b1,
                                              const float* __restrict__ b2,
                                              float* __restrict__ ub){
  int w = threadIdx.x >> 6, l = threadIdx.x & 63;
  const float* b = w ? b2 : b1;
  float bv = b[l];
  float tb = l ? bv : 0.f;
  float s  = wredsum(tb*tb);
  float xn = fmaxf(sqrtf(s), MINN);
  float sc = sinhf(xn)/xn;
  float e  = sc*tb;
  float s2 = wredsum(e*e);
  float x0 = sqrtf(fmaxf(1.f+s2, EPSF));
  float yn = fmaxf(sqrtf(s2), MINN);
  float th = fmaxf(x0, 1.f+EPSF);
  float u  = l ? acoshf(th)*e/yn : 0.f;
  ub[w*64 + l] = u;
}

// ---- per-row linear + mobius bias chain -> g
template<int MODE>
__global__ __launch_bounds__(256) void k_linear(const float* __restrict__ in,
                                                const float* __restrict__ W,
                                                const float* __restrict__ ub,
                                                float* __restrict__ g){
  __shared__ float Wt[64*65];
  int tid = threadIdx.x;
  for(int idx = tid; idx < 4096; idx += 256){
    int j = idx >> 6, k = idx & 63;
    Wt[k*65 + j] = W[idx];
  }
  __syncthreads();
  int lane = tid & 63;
  int row  = blockIdx.x*4 + (tid >> 6);
  float v = in[(size_t)row*64 + lane];
  float lx;
  if (MODE == 0){
    float t  = lane ? v : 0.f;
    float s  = wredsum(t*t);
    float tn = fmaxf(sqrtf(s), MINN);
    float sc = sinhf(tn)/tn;
    float e  = sc*t;
    float s2 = wredsum(e*e);
    float x0 = sqrtf(fmaxf(1.f+s2, EPSF));
    float yn = fmaxf(sqrtf(s2), MINN);
    float th = fmaxf(x0, 1.f+EPSF);
    lx = lane ? acoshf(th)*e/yn : 0.f;
  } else {
    float t  = lane ? v : 0.f;
    float s2 = wredsum(t*t);
    float x0 = __shfl(v, 0);
    float yn = fmaxf(sqrtf(s2), MINN);
    float th = fmaxf(x0, 1.f+EPSF);
    lx = lane ? acoshf(th)*t/yn : 0.f;
  }
  float mv = 0.f;
  #pragma unroll
  for(int k = 0; k < 64; k++){
    mv = fmaf(__shfl(lx, k), Wt[k*65 + lane], mv);
  }
  float u  = lane ? mv : 0.f;
  float s  = wredsum(u*u);
  float un = fmaxf(sqrtf(s), MINN);
  float sc = sinhf(un)/un;
  float e  = sc*u;
  float s2 = wredsum(e*e);
  float r0 = sqrtf(fmaxf(1.f+s2, EPSF));
  float ubt   = lane ? ub[lane] : 0.f;
  float yn    = fmaxf(sqrtf(s2), MINN);
  float yhat  = e/yn;
  float alpha = wredsum(yhat*ubt);
  float w     = ubt - alpha*(1.f - r0)*yhat;
  float ux    = wredsum(e*w);
  float v0    = ux / fmaxf(r0, EPSF);
  float md    = wredsum(w*w) - v0*v0;
  float normu = fminf(sqrtf(fmaxf(md, EPSF)), MAXN);
  float th2   = fmaxf(normu, MINN);
  float ch    = coshf(th2);
  float shq   = sinhf(th2)/th2;
  float ov    = ch*(lane ? e : r0) + shq*(lane ? w : v0);
  float ot    = lane ? ov : 0.f;
  float s3    = wredsum(ot*ot);
  float o0    = sqrtf(fmaxf(1.f+s3, EPSF));
  float yn2 = fmaxf(sqrtf(s3), MINN);
  float th3 = fmaxf(o0, 1.f+EPSF);
  float gv  = lane ? acoshf(th3)*ot/yn2 : 0.f;
  g[(size_t)row*64 + lane] = gv;
}

// ---- transpose + bf16 convert: g[N][64] f32 -> gT[64][N] bf16
__global__ __launch_bounds__(256) void k_tr(const float* __restrict__ g,
                                            short* __restrict__ gT){
  __shared__ float t[64][65];
  int tid = threadIdx.x;
  int b   = blockIdx.x;
  int r   = tid >> 2;
  int c0  = (tid & 3)*16;
  const float* src = g + ((size_t)b*64 + r)*64 + c0;
  #pragma unroll
  for(int i = 0; i < 4; i++){
    float4 v = *(const float4*)(src + i*4);
    t[r][c0 + i*4 + 0] = v.x; t[r][c0 + i*4 + 1] = v.y;
    t[r][c0 + i*4 + 2] = v.z; t[r][c0 + i*4 + 3] = v.w;
  }
  __syncthreads();
  int n   = tid >> 2;
  int seg = tid & 3;
  short8 p0, p1;
  #pragma unroll
  for(int j = 0; j < 8; j++) p0[j] = (short)f2bf(t[seg*16 + j][n]);
  #pragma unroll
  for(int j = 0; j < 8; j++) p1[j] = (short)f2bf(t[seg*16 + 8 + j][n]);
  short* dst = gT + (size_t)n*KDIM + b*64 + seg*16;
  *(short8*)(dst)     = p0;
  *(short8*)(dst + 8) = p1;
}

// ---- full-K MFMA matmul, double-buffered LDS, counted-vmcnt barriers (no drain):
// agg[row][n] = adj[row,:] @ g[:,n] ; prsum[row] = sum(adj[row,:]) if FIRST
template<bool FIRST>
__global__ __launch_bounds__(512) void k_matmul(const float* __restrict__ adj,
                                                const short* __restrict__ gT,
                                                float* __restrict__ agg,
                                                float* __restrict__ prsum){
  __shared__ __align__(16) char lds[2*ABUF + 2*BBUF];   // ~25 KB
  char* A0 = lds;
  char* A1 = lds + ABUF;
  char* B0 = lds + 2*ABUF;
  char* B1 = lds + 2*ABUF + BBUF;
  int tid  = threadIdx.x;
  int lane = tid & 63, w = tid >> 6;
  int row0 = blockIdx.x * BM;

  // A staging: thread -> (row r, k-quad kq); coalesced float4
  int r  = tid >> 4;                 // 0..31
  int kq = tid & 15;                 // 16 quads = 64 k
  const float* ap = adj + (size_t)(row0 + r)*KDIM + kq*4;
  int AwOff = (kq >> 1)*APG + r*16 + (kq & 1)*8;

  // B staging: thread -> (col nB, k-octet q2); contiguous short8 from gT row
  int nB = tid & 63;
  int q2 = tid >> 6;                 // 0..7
  const short* bp = gT + (size_t)nB*KDIM + q2*8;
  int BwOff = q2*BPG + nB*16;

  // fragment roles: wave (wm,wn) computes rows wm*16..+16, cols wn*16..+16
  int wm = w >> 2, wn = w & 3;
  int fr = lane & 15, fk = lane >> 4;
  int ArdOff = fk*APG + (wm*16 + fr)*16;
  int BrdOff = fk*BPG + (wn*16 + fr)*16;

  f32x4 acc = {0.f,0.f,0.f,0.f};
  float rs = 0.f;

  // prologue: stage step 0 into buf0; preload steps 1 (P) and 2 (Q)
  {
    float4 a0 = *(const float4*)(ap);
    short8 b0v = *(const short8*)(bp);
    if (FIRST) rs += a0.x + a0.y + a0.z + a0.w;
    u16x4 ak = { f2bf(a0.x), f2bf(a0.y), f2bf(a0.z), f2bf(a0.w) };
    *(u16x4*)(A0 + AwOff) = ak;
    *(short8*)(B0 + BwOff) = b0v;
  }
  float4 aP = *(const float4*)(ap + BK2);
  short8 bP = *(const short8*)(bp + BK2);
  float4 aQ = *(const float4*)(ap + 2*BK2);
  short8 bQ = *(const short8*)(bp + 2*BK2);
  BARL();

  for (int k = 0; k < NSTEP2; k += 2){
    // ===== even half: compute step k from buf0; stage step k+1 -> buf1
    {
      short8 af0 = *(const short8*)(A0 + ArdOff);
      short8 af1 = *(const short8*)(A0 + ArdOff + 4*APG);
      short8 bf0 = *(const short8*)(B0 + BrdOff);
      short8 bf1 = *(const short8*)(B0 + BrdOff + 4*BPG);
      // stage k+1 (aP/bP loaded ~2 steps ago; counted vmcnt wait here)
      if (FIRST) rs += aP.x + aP.y + aP.z + aP.w;
      u16x4 ak = { f2bf(aP.x), f2bf(aP.y), f2bf(aP.z), f2bf(aP.w) };
      *(u16x4*)(A1 + AwOff) = ak;
      *(short8*)(B1 + BwOff) = bP;
      // refill P with step k+3
      if (k + 3 < NSTEP2){
        aP = *(const float4*)(ap + (size_t)(k+3)*BK2);
        bP = *(const short8*)(bp + (size_t)(k+3)*BK2);
      }
      acc = __builtin_amdgcn_mfma_f32_16x16x32_bf16(af0, bf0, acc, 0, 0, 0);
      acc = __builtin_amdgcn_mfma_f32_16x16x32_bf16(af1, bf1, acc, 0, 0, 0);
    }
    BARL();
    // ===== odd half: compute step k+1 from buf1; stage step k+2 -> buf0
    {
      short8 af0 = *(const short8*)(A1 + ArdOff);
      short8 af1 = *(const short8*)(A1 + ArdOff + 4*APG);
      short8 bf0 = *(const short8*)(B1 + BrdOff);
      short8 bf1 = *(const short8*)(B1 + BrdOff + 4*BPG);
      if (k + 2 < NSTEP2){
        if (FIRST) rs += aQ.x + aQ.y + aQ.z + aQ.w;
        u16x4 ak = { f2bf(aQ.x), f2bf(aQ.y), f2bf(aQ.z), f2bf(aQ.w) };
        *(u16x4*)(A0 + AwOff) = ak;
        *(short8*)(B0 + BwOff) = bQ;
      }
      if (k + 4 < NSTEP2){
        aQ = *(const float4*)(ap + (size_t)(k+4)*BK2);
        bQ = *(const short8*)(bp + (size_t)(k+4)*BK2);
      }
      acc = __builtin_amdgcn_mfma_f32_16x16x32_bf16(af0, bf0, acc, 0, 0, 0);
      acc = __builtin_amdgcn_mfma_f32_16x16x32_bf16(af1, bf1, acc, 0, 0, 0);
    }
    BARL();
  }

  if (FIRST){
    rs += __shfl_xor(rs, 1);
    rs += __shfl_xor(rs, 2);
    rs += __shfl_xor(rs, 4);
    rs += __shfl_xor(rs, 8);
    if ((lane & 15) == 0) prsum[row0 + r] = rs;   // r = w*4 + (lane>>4)
  }
  // C write: D layout n = lane&15, m = (lane>>4)*4 + q
  float* ob = agg + (size_t)(row0 + wm*16)*64 + wn*16;
  #pragma unroll
  for(int q = 0; q < 4; q++){
    ob[(size_t)((lane >> 4)*4 + q)*64 + (lane & 15)] = acc[q];
  }
}

// ---- fused: (layer1: rinv compute/store) + postagg chain -> h
template<int LAYER>
__global__ __launch_bounds__(256) void k_post(const float* __restrict__ agg,
                                              const float* __restrict__ prsum,
                                              float* __restrict__ rinv,
                                              float* __restrict__ h){
  int tid = threadIdx.x; int lane = tid & 63;
  int row = blockIdx.x*4 + (tid >> 6);
  float s = agg[(size_t)row*64 + lane];
  float ri;
  if (LAYER == 1){
    float rsum = prsum[row];
    ri = (rsum != 0.f) ? 1.f/rsum : 0.f;
    if (lane == 0) rinv[row] = ri;
  } else {
    ri = rinv[row];
  }
  float a  = s * ri;
  float at = lane ? a : 0.f;
  float ss = wredsum(at*at);
  float un = fmaxf(sqrtf(ss), MINN);
  float sc = sinhf(un)/un;
  float e  = sc*at;
  float s2 = wredsum(e*e);
  float x0 = sqrtf(fmaxf(1.f+s2, EPSF));
  float yn = fmaxf(sqrtf(s2), MINN);
  float th = fmaxf(x0, 1.f+EPSF);
  float lt = lane ? acoshf(th)*e/yn : 0.f;
  float rl = fmaxf(lt, 0.f);
  float s3 = wredsum(rl*rl);
  float rn = fmaxf(sqrtf(s3), MINN);
  float sc2= sinhf(rn)/rn;
  float e2 = sc2*rl;
  float s4 = wredsum(e2*e2);
  float h0 = sqrtf(fmaxf(1.f+s4, EPSF));
  h[(size_t)row*64 + lane] = lane ? e2 : h0;
}

extern "C" void kernel_launch(void* const* d_in, const int* in_sizes, int n_in,
                              void* d_out, int out_size, void* d_ws, size_t ws_size,
                              hipStream_t stream){
  const float* x   = (const float*)d_in[0];
  const float* adj = (const float*)d_in[1];
  const float* W1  = (const float*)d_in[2];
  const float* b1  = (const float*)d_in[3];
  const float* W2  = (const float*)d_in[4];
  const float* b2  = (const float*)d_in[5];
  float* out = (float*)d_out;
  float* h1  = out;
  float* h2  = out + (size_t)NROWS*64;

  float* wsf   = (float*)d_ws;
  float* gbuf  = wsf;                              // N*64 f32
  float* aggb  = gbuf  + (size_t)NROWS*64;         // N*64 f32
  float* prsum = aggb  + (size_t)NROWS*64;         // N
  float* rinv  = prsum + NROWS;                    // N
  float* ubs   = rinv  + NROWS;                    // 128
  short* gT    = (short*)(ubs + 128);              // 64*N bf16

  k_bias<<<1, 128, 0, stream>>>(b1, b2, ubs);
  // layer 1
  k_linear<0><<<NROWS/4, 256, 0, stream>>>(x, W1, ubs, gbuf);
  k_tr<<<NROWS/64, 256, 0, stream>>>(gbuf, gT);
  k_matmul<true><<<NROWS/BM, 512, 0, stream>>>(adj, gT, aggb, prsum);
  k_post<1><<<NROWS/4, 256, 0, stream>>>(aggb, prsum, rinv, h1);
  // layer 2
  k_linear<1><<<NROWS/4, 256, 0, stream>>>(h1, W2, ubs + 64, gbuf);
  k_tr<<<NROWS/64, 256, 0, stream>>>(gbuf, gT);
  k_matmul<false><<<NROWS/BM, 512, 0, stream>>>(adj, gT, aggb, prsum);
  k_post<2><<<NROWS/4, 256, 0, stream>>>(aggb, prsum, rinv, h2);
}

// Round 7
// 666.177 us; speedup vs baseline: 1.0239x; 1.0239x over previous
//
#include <hip/hip_runtime.h>
#include <cstdint>
#include <cstddef>

#define NROWS 16384
#define KDIM  16384
#define EPSF  1e-7f
#define MINN  1e-15f
#define MAXN  1e6f
#define KSPLIT 4
#define KRANGE (KDIM/KSPLIT)   /* 4096 */
#define BM    32               /* rows per block */
#define BK    128              /* K per step: 512B contiguous per row */
#define NSTEP (KRANGE/BK)      /* 32 */
#define NPAGE 16               /* BK/8 k-octet pages */
#define APG   528              /* A page: 32 rows*16B + 16 pad */
#define BPG   1040             /* B page: 64 cols*16B + 16 pad */
#define ABUF  (NPAGE*APG)      /* 8448 */
#define BBUF  (NPAGE*BPG)      /* 16640 */

typedef __attribute__((ext_vector_type(8))) short short8;
typedef __attribute__((ext_vector_type(4))) float f32x4;
typedef __attribute__((ext_vector_type(4))) unsigned short u16x4;

__device__ __forceinline__ unsigned short f2bf(float f){
  union { float f; unsigned u; } c; c.f = f;
  unsigned u = c.u;
  unsigned r = (u + 0x7FFFu + ((u >> 16) & 1u)) >> 16;   // RNE
  return (unsigned short)r;
}

__device__ __forceinline__ float wredsum(float v){
  v += __shfl_xor(v, 1);
  v += __shfl_xor(v, 2);
  v += __shfl_xor(v, 4);
  v += __shfl_xor(v, 8);
  v += __shfl_xor(v, 16);
  v += __shfl_xor(v, 32);
  return v;
}

// ---- ub = logmap0(proj(expmap0(proj_tan0(b)))) for b1 (wave0) and b2 (wave1)
__global__ __launch_bounds__(128) void k_bias(const float* __restrict__ b1,
                                              const float* __restrict__ b2,
                                              float* __restrict__ ub){
  int w = threadIdx.x >> 6, l = threadIdx.x & 63;
  const float* b = w ? b2 : b1;
  float bv = b[l];
  float tb = l ? bv : 0.f;
  float s  = wredsum(tb*tb);
  float xn = fmaxf(sqrtf(s), MINN);
  float sc = sinhf(xn)/xn;
  float e  = sc*tb;
  float s2 = wredsum(e*e);
  float x0 = sqrtf(fmaxf(1.f+s2, EPSF));
  float yn = fmaxf(sqrtf(s2), MINN);
  float th = fmaxf(x0, 1.f+EPSF);
  float u  = l ? acoshf(th)*e/yn : 0.f;
  ub[w*64 + l] = u;
}

// ---- per-row linear + mobius bias chain -> g
template<int MODE>
__global__ __launch_bounds__(256) void k_linear(const float* __restrict__ in,
                                                const float* __restrict__ W,
                                                const float* __restrict__ ub,
                                                float* __restrict__ g){
  __shared__ float Wt[64*65];
  int tid = threadIdx.x;
  for(int idx = tid; idx < 4096; idx += 256){
    int j = idx >> 6, k = idx & 63;
    Wt[k*65 + j] = W[idx];
  }
  __syncthreads();
  int lane = tid & 63;
  int row  = blockIdx.x*4 + (tid >> 6);
  float v = in[(size_t)row*64 + lane];
  float lx;
  if (MODE == 0){
    float t  = lane ? v : 0.f;
    float s  = wredsum(t*t);
    float tn = fmaxf(sqrtf(s), MINN);
    float sc = sinhf(tn)/tn;
    float e  = sc*t;
    float s2 = wredsum(e*e);
    float x0 = sqrtf(fmaxf(1.f+s2, EPSF));
    float yn = fmaxf(sqrtf(s2), MINN);
    float th = fmaxf(x0, 1.f+EPSF);
    lx = lane ? acoshf(th)*e/yn : 0.f;
  } else {
    float t  = lane ? v : 0.f;
    float s2 = wredsum(t*t);
    float x0 = __shfl(v, 0);
    float yn = fmaxf(sqrtf(s2), MINN);
    float th = fmaxf(x0, 1.f+EPSF);
    lx = lane ? acoshf(th)*t/yn : 0.f;
  }
  float mv = 0.f;
  #pragma unroll
  for(int k = 0; k < 64; k++){
    mv = fmaf(__shfl(lx, k), Wt[k*65 + lane], mv);
  }
  float u  = lane ? mv : 0.f;
  float s  = wredsum(u*u);
  float un = fmaxf(sqrtf(s), MINN);
  float sc = sinhf(un)/un;
  float e  = sc*u;
  float s2 = wredsum(e*e);
  float r0 = sqrtf(fmaxf(1.f+s2, EPSF));
  float ubt   = lane ? ub[lane] : 0.f;
  float yn    = fmaxf(sqrtf(s2), MINN);
  float yhat  = e/yn;
  float alpha = wredsum(yhat*ubt);
  float w     = ubt - alpha*(1.f - r0)*yhat;
  float ux    = wredsum(e*w);
  float v0    = ux / fmaxf(r0, EPSF);
  float md    = wredsum(w*w) - v0*v0;
  float normu = fminf(sqrtf(fmaxf(md, EPSF)), MAXN);
  float th2   = fmaxf(normu, MINN);
  float ch    = coshf(th2);
  float shq   = sinhf(th2)/th2;
  float ov    = ch*(lane ? e : r0) + shq*(lane ? w : v0);
  float ot    = lane ? ov : 0.f;
  float s3    = wredsum(ot*ot);
  float o0    = sqrtf(fmaxf(1.f+s3, EPSF));
  float yn2 = fmaxf(sqrtf(s3), MINN);
  float th3 = fmaxf(o0, 1.f+EPSF);
  float gv  = lane ? acoshf(th3)*ot/yn2 : 0.f;
  g[(size_t)row*64 + lane] = gv;
}

// ---- transpose + bf16 convert: g[N][64] f32 -> gT[64][N] bf16
__global__ __launch_bounds__(256) void k_tr(const float* __restrict__ g,
                                            short* __restrict__ gT){
  __shared__ float t[64][65];
  int tid = threadIdx.x;
  int b   = blockIdx.x;
  int r   = tid >> 2;
  int c0  = (tid & 3)*16;
  const float* src = g + ((size_t)b*64 + r)*64 + c0;
  #pragma unroll
  for(int i = 0; i < 4; i++){
    float4 v = *(const float4*)(src + i*4);
    t[r][c0 + i*4 + 0] = v.x; t[r][c0 + i*4 + 1] = v.y;
    t[r][c0 + i*4 + 2] = v.z; t[r][c0 + i*4 + 3] = v.w;
  }
  __syncthreads();
  int n   = tid >> 2;
  int seg = tid & 3;
  short8 p0, p1;
  #pragma unroll
  for(int j = 0; j < 8; j++) p0[j] = (short)f2bf(t[seg*16 + j][n]);
  #pragma unroll
  for(int j = 0; j < 8; j++) p1[j] = (short)f2bf(t[seg*16 + 8 + j][n]);
  short* dst = gT + (size_t)n*KDIM + b*64 + seg*16;
  *(short8*)(dst)     = p0;
  *(short8*)(dst + 8) = p1;
}

// ---- MFMA split-K matmul: BK=128, double-buffered LDS, 1 barrier/step, 3 blocks/CU.
// pagg[ks] = adj[:, krange] @ g[krange, :]; rowsum partials if FIRST
#define STAGE_A(Ab) do{                                                        \
  _Pragma("unroll")                                                            \
  for(int q = 0; q < 4; q++){                                                  \
    if (FIRST) rs += aR[q].x + aR[q].y + aR[q].z + aR[q].w;                    \
    u16x4 ak = { f2bf(aR[q].x), f2bf(aR[q].y), f2bf(aR[q].z), f2bf(aR[q].w) }; \
    *(u16x4*)((Ab) + (seg*2 + (q>>1))*APG + r*16 + (q&1)*8) = ak;              \
  } }while(0)

#define STAGE_B(Bb) do{                                                        \
  _Pragma("unroll")                                                            \
  for(int j = 0; j < 4; j++){                                                  \
    *(short8*)((Bb) + (qd*4 + j)*BPG + nB*16) = bR[j];                         \
  } }while(0)

template<bool FIRST>
__global__ __launch_bounds__(256, 3) void k_matmul(const float* __restrict__ adj,
                                                   const short* __restrict__ gT,
                                                   float* __restrict__ pagg,
                                                   float* __restrict__ prsum){
  __shared__ __align__(16) char lds[2*(ABUF + BBUF)];   // ~49 KB -> 3 blocks/CU
  int tid  = threadIdx.x;
  int lane = tid & 63, w = tid >> 6;
  int rb   = blockIdx.x;               // rb in LOW grid bits (R2-proven)
  int ks   = blockIdx.y;
  int row0 = rb*BM;
  size_t k0 = (size_t)ks * KRANGE;

  // A staging: thread (row r, 64B-seg): 4 consecutive float4 (512B/row per 8 lanes)
  int r   = tid >> 3;                  // 0..31
  int seg = tid & 7;                   // 0..7
  const float* ap = adj + (size_t)(row0 + r)*KDIM + k0 + seg*16;

  // B staging: thread (col nB, 32k-chunk qd): 4 consecutive short8 (64B) from gT row
  int nB = tid & 63;
  int qd = tid >> 6;                   // 0..3
  const short* bp = gT + (size_t)nB*KDIM + k0 + qd*32;

  // fragment roles: wave w: rows (w&1)*16, cols (w>>1)*32
  int wm = w & 1, wn = w >> 1;
  int fr = lane & 15, fk = lane >> 4;

  f32x4 acc[2] = {{0.f,0.f,0.f,0.f},{0.f,0.f,0.f,0.f}};
  float rs = 0.f;

  float4 aR[4], aN[4];
  short8 bR[4], bN[4];

  // prologue: load + stage step 0 into buf0; load step 1
  #pragma unroll
  for(int q = 0; q < 4; q++) aR[q] = *(const float4*)(ap + q*4);
  #pragma unroll
  for(int j = 0; j < 4; j++) bR[j] = *(const short8*)(bp + j*8);
  STAGE_A(lds);
  STAGE_B(lds + ABUF);
  #pragma unroll
  for(int q = 0; q < 4; q++) aR[q] = *(const float4*)(ap + BK + q*4);
  #pragma unroll
  for(int j = 0; j < 4; j++) bR[j] = *(const short8*)(bp + BK + j*8);
  __syncthreads();

  for (int i = 0; i < NSTEP; i++){
    const char* Ab = lds + (i & 1)*(ABUF + BBUF);
    const char* Bb = Ab + ABUF;
    short8 af[4], bf0[4], bf1[4];
    #pragma unroll
    for(int kb = 0; kb < 4; kb++){
      af[kb]  = *(const short8*)(Ab + (kb*4 + fk)*APG + (wm*16 + fr)*16);
      bf0[kb] = *(const short8*)(Bb + (kb*4 + fk)*BPG + (wn*32 + fr)*16);
      bf1[kb] = *(const short8*)(Bb + (kb*4 + fk)*BPG + (wn*32 + 16 + fr)*16);
    }
    if (i + 1 < NSTEP){
      char* Nb = lds + ((i+1) & 1)*(ABUF + BBUF);
      STAGE_A(Nb);
      STAGE_B(Nb + ABUF);
    }
    if (i + 2 < NSTEP){
      const float* ap2 = ap + (size_t)(i+2)*BK;
      #pragma unroll
      for(int q = 0; q < 4; q++) aN[q] = *(const float4*)(ap2 + q*4);
      const short* bp2 = bp + (size_t)(i+2)*BK;
      #pragma unroll
      for(int j = 0; j < 4; j++) bN[j] = *(const short8*)(bp2 + j*8);
    }
    #pragma unroll
    for(int kb = 0; kb < 4; kb++){
      acc[0] = __builtin_amdgcn_mfma_f32_16x16x32_bf16(af[kb], bf0[kb], acc[0], 0, 0, 0);
      acc[1] = __builtin_amdgcn_mfma_f32_16x16x32_bf16(af[kb], bf1[kb], acc[1], 0, 0, 0);
    }
    #pragma unroll
    for(int q = 0; q < 4; q++) aR[q] = aN[q];
    #pragma unroll
    for(int j = 0; j < 4; j++) bR[j] = bN[j];
    __syncthreads();
  }

  if (FIRST){
    rs += __shfl_xor(rs, 1);
    rs += __shfl_xor(rs, 2);
    rs += __shfl_xor(rs, 4);
    if ((lane & 7) == 0) prsum[(size_t)ks*NROWS + row0 + r] = rs;
  }
  // C write: D layout n = lane&15, m = (lane>>4)*4 + q
  float* ob = pagg + ((size_t)ks*NROWS + row0 + wm*16)*64 + wn*32;
  #pragma unroll
  for(int c = 0; c < 2; c++){
    #pragma unroll
    for(int q = 0; q < 4; q++){
      ob[(size_t)((lane >> 4)*4 + q)*64 + c*16 + (lane & 15)] = acc[c][q];
    }
  }
}

// ---- fused: split-K reduce + (layer1: rinv compute/store) + postagg chain -> h
template<int LAYER>
__global__ __launch_bounds__(256) void k_post(const float* __restrict__ pagg,
                                              const float* __restrict__ prsum,
                                              float* __restrict__ rinv,
                                              float* __restrict__ h){
  int tid = threadIdx.x; int lane = tid & 63;
  int row = blockIdx.x*4 + (tid >> 6);
  float s = 0.f;
  #pragma unroll
  for(int ks = 0; ks < KSPLIT; ks++) s += pagg[(size_t)ks*NROWS*64 + (size_t)row*64 + lane];
  float ri;
  if (LAYER == 1){
    float rsum = 0.f;
    #pragma unroll
    for(int ks = 0; ks < KSPLIT; ks++) rsum += prsum[(size_t)ks*NROWS + row];
    ri = (rsum != 0.f) ? 1.f/rsum : 0.f;
    if (lane == 0) rinv[row] = ri;
  } else {
    ri = rinv[row];
  }
  float a  = s * ri;
  float at = lane ? a : 0.f;
  float ss = wredsum(at*at);
  float un = fmaxf(sqrtf(ss), MINN);
  float sc = sinhf(un)/un;
  float e  = sc*at;
  float s2 = wredsum(e*e);
  float x0 = sqrtf(fmaxf(1.f+s2, EPSF));
  float yn = fmaxf(sqrtf(s2), MINN);
  float th = fmaxf(x0, 1.f+EPSF);
  float lt = lane ? acoshf(th)*e/yn : 0.f;
  float rl = fmaxf(lt, 0.f);
  float s3 = wredsum(rl*rl);
  float rn = fmaxf(sqrtf(s3), MINN);
  float sc2= sinhf(rn)/rn;
  float e2 = sc2*rl;
  float s4 = wredsum(e2*e2);
  float h0 = sqrtf(fmaxf(1.f+s4, EPSF));
  h[(size_t)row*64 + lane] = lane ? e2 : h0;
}

extern "C" void kernel_launch(void* const* d_in, const int* in_sizes, int n_in,
                              void* d_out, int out_size, void* d_ws, size_t ws_size,
                              hipStream_t stream){
  const float* x   = (const float*)d_in[0];
  const float* adj = (const float*)d_in[1];
  const float* W1  = (const float*)d_in[2];
  const float* b1  = (const float*)d_in[3];
  const float* W2  = (const float*)d_in[4];
  const float* b2  = (const float*)d_in[5];
  float* out = (float*)d_out;
  float* h1  = out;
  float* h2  = out + (size_t)NROWS*64;

  float* wsf   = (float*)d_ws;
  float* gbuf  = wsf;                              // N*64 f32
  float* pagg  = gbuf  + (size_t)NROWS*64;         // KSPLIT*N*64 f32
  float* prsum = pagg  + (size_t)KSPLIT*NROWS*64;  // KSPLIT*N
  float* rinv  = prsum + (size_t)KSPLIT*NROWS;     // N
  float* ubs   = rinv  + NROWS;                    // 128
  short* gT    = (short*)(ubs + 128);              // 64*N bf16

  dim3 gm(NROWS/BM, KSPLIT);                       // rb in LOW bits

  k_bias<<<1, 128, 0, stream>>>(b1, b2, ubs);
  // layer 1
  k_linear<0><<<NROWS/4, 256, 0, stream>>>(x, W1, ubs, gbuf);
  k_tr<<<NROWS/64, 256, 0, stream>>>(gbuf, gT);
  k_matmul<true><<<gm, 256, 0, stream>>>(adj, gT, pagg, prsum);
  k_post<1><<<NROWS/4, 256, 0, stream>>>(pagg, prsum, rinv, h1);
  // layer 2
  k_linear<1><<<NROWS/4, 256, 0, stream>>>(h1, W2, ubs + 64, gbuf);
  k_tr<<<NROWS/64, 256, 0, stream>>>(gbuf, gT);
  k_matmul<false><<<gm, 256, 0, stream>>>(adj, gT, pagg, prsum);
  k_post<2><<<NROWS/4, 256, 0, stream>>>(pagg, prsum, rinv, h2);
}